// Round 5
// baseline (272.658 us; speedup 1.0000x reference)
//
#include <hip/hip_runtime.h>
#include <hip/hip_bf16.h>
#include <string.h>

// DeformableConv2d: B=4, C=256, O=256, H=W=64, K=3, pad=1, stride=1
// Round 15: K3 LDS diet -> 2 blocks/CU (one change vs r14).
//   r14 post-mortem: K2 rewrite landed (-7.5us). K3 (45us) again the big
//   controllable chunk: MfmaUtil 17 / VALUBusy 32 / Occupancy 19% -> ~50%
//   of cycles are waits; nothing saturated (unlike r11's TA-bound null).
//   Blocker is LDS 84992 B > 80KiB -> 1 block/CU. Diet: params 18432 ->
//   paramw float4 (9216) + paramo ushort4 pixel-indices (4608, byte off =
//   idx<<9, bit-identical); ua[16] -> ua[8] x2 batches (frees 32 VGPR for
//   the __launch_bounds__(512,4) cap). New LDS 80384 <= 81920 -> 2
//   blocks/CU = 4 waves/SIMD. vmcnt pipeline order preserved:
//   ua1,gatherA,ua2 | mfma0-7(ua1) packA(gA) gatherB | mfma8-15(ua2)
//   packB(gB). Addresses and arithmetic identical -> absmax 0.0078125.
// K0, K1, K2 byte-identical to round 14.
// Workspace: ws_off 1769472 | ws_b 1179648 | ws_a2 147456 | xt 8388608
//          = 11,485,184 B.

typedef __attribute__((ext_vector_type(8))) short short8;
typedef __attribute__((ext_vector_type(8))) _Float16 half8;
typedef __attribute__((ext_vector_type(16))) float floatx16;

__device__ __forceinline__ unsigned bfbits(float f) {
    unsigned u;
    __builtin_memcpy(&u, &f, 4);
    return (u + 0x7fffu + ((u >> 16) & 1u)) >> 16;   // RNE f32->bf16
}
__device__ __forceinline__ unsigned pack_bf16(float lo, float hi) {
    return bfbits(lo) | (bfbits(hi) << 16);
}
__device__ __forceinline__ unsigned pack_f16(float lo, float hi) {
    _Float16 a = (_Float16)lo, b = (_Float16)hi;
    unsigned short ua, ub;
    __builtin_memcpy(&ua, &a, 2);
    __builtin_memcpy(&ub, &b, 2);
    return (unsigned)ua | ((unsigned)ub << 16);
}

// async global->LDS DMA, 16 B per lane; lane l's data lands at lds + l*16.
// Global source address is PER-LANE (enables write-side swizzle).
__device__ __forceinline__ void gl_lds16(const void* g, void* l) {
    __builtin_amdgcn_global_load_lds(
        (const __attribute__((address_space(1))) unsigned int*)g,
        (__attribute__((address_space(3))) unsigned int*)l,
        16, 0, 0);
}

// ---------------------------------------------------------------------------
// K0: x (B,C,H,W) f32 -> xt (B,H,W,C) f16.  One block per (b, y) row.
// (verbatim rounds 12-14)
// ---------------------------------------------------------------------------
__global__ __launch_bounds__(256) void xpose_hwc_kernel(
    const float* __restrict__ x, unsigned short* __restrict__ xt)
{
    __shared__ float stage[256 * 65];
    const int bid = blockIdx.x;          // (b*64 + y)
    const int b = bid >> 6, y = bid & 63;
    const int tid = threadIdx.x;
    const float* src = x + (size_t)b * 256 * 4096 + y * 64;

#pragma unroll
    for (int i = 0; i < 16; ++i) {
        int idx = i * 256 + tid;         // 0..4095 = (c, xq)
        int c = idx >> 4, xq = idx & 15;
        float4 v = *(const float4*)&src[(size_t)c * 4096 + xq * 4];
        stage[c * 65 + xq * 4 + 0] = v.x;
        stage[c * 65 + xq * 4 + 1] = v.y;
        stage[c * 65 + xq * 4 + 2] = v.z;
        stage[c * 65 + xq * 4 + 3] = v.w;
    }
    __syncthreads();

    unsigned short* dst = xt + (size_t)bid * 16384;   // 64 px * 256 ch
#pragma unroll
    for (int i = 0; i < 32; ++i) {
        int c2 = (tid & 127) * 2;
        int xx = i * 2 + (tid >> 7);
        float f0 = stage[c2 * 65 + xx];
        float f1 = stage[(c2 + 1) * 65 + xx];
        *(unsigned*)&dst[xx * 256 + c2] = pack_f16(f0, f1);
    }
}

// ---------------------------------------------------------------------------
// K1: weight pack (verbatim rounds 4-14).
// ---------------------------------------------------------------------------
__global__ __launch_bounds__(256) void weight_pack_kernel(
    const float* __restrict__ w, const float* __restrict__ off_w,
    const float* __restrict__ mask_w,
    unsigned short* __restrict__ ws_b, unsigned short* __restrict__ ws_a2)
{
    __shared__ float slab[32 * 289];
    const int bid = blockIdx.x;
    const int tid = threadIdx.x;

    if (bid < 64) {
        const int nt = bid >> 3, cb = bid & 7;
        const float* wbase = w + (size_t)nt * 32 * 2304 + cb * 288;
#pragma unroll
        for (int i = 0; i < 9; ++i) {
            int idx = i * 256 + tid;               // 0..2303
            int o = idx / 72, f4 = idx % 72;
            float4 v = *(const float4*)&wbase[(size_t)o * 2304 + f4 * 4];
            slab[o * 289 + f4 * 4 + 0] = v.x;
            slab[o * 289 + f4 * 4 + 1] = v.y;
            slab[o * 289 + f4 * 4 + 2] = v.z;
            slab[o * 289 + f4 * 4 + 3] = v.w;
        }
        __syncthreads();
#pragma unroll
        for (int pass = 0; pass < 5; ++pass) {
            int rid = pass * 8 + (tid >> 5);
            if (rid < 36) {
                int kk = rid >> 2, q = rid & 3;
                int no = tid & 31;
                unsigned pk[4];
#pragma unroll
                for (int i = 0; i < 4; ++i) {
                    float f0 = slab[no * 289 + (q * 8 + 2 * i) * 9 + kk];
                    float f1 = slab[no * 289 + (q * 8 + 2 * i + 1) * 9 + kk];
                    pk[i] = pack_bf16(f0, f1);
                }
                size_t u = ((size_t)nt * 288 + kk * 32 + cb * 4 + q) * 32 + no;
                *(uint4*)&ws_b[u * 8] = make_uint4(pk[0], pk[1], pk[2], pk[3]);
            }
        }
    } else {
        int e = (bid - 64) * 256 + tid;       // 0..9215
        int lan = e & 31;                     // oc row
        int ku = e >> 5;                      // 0..287
        int kk = ku >> 5;
        int c0 = (ku & 31) * 8;
        int o = lan;
        float f[8];
#pragma unroll
        for (int j = 0; j < 8; ++j) {
            int c = c0 + j;
            float v = 0.f;
            if (o < 18)      v = off_w[((size_t)o * 256 + c) * 9 + kk];
            else if (o < 27) v = mask_w[((size_t)(o - 18) * 256 + c) * 9 + kk];
            f[j] = v;
        }
        unsigned pk[4];
#pragma unroll
        for (int i = 0; i < 4; ++i) pk[i] = pack_f16(f[2 * i], f[2 * i + 1]);
        *(uint4*)&ws_a2[(size_t)e * 8] = make_uint4(pk[0], pk[1], pk[2], pk[3]);
    }
}

// ---------------------------------------------------------------------------
// K2: offset/mask conv, xt-direct edition (verbatim round 14).
// ---------------------------------------------------------------------------
__global__ __launch_bounds__(512) void offmask_mfma_kernel(
    const unsigned short* __restrict__ xt, const unsigned short* __restrict__ ws_a2,
    const float* __restrict__ off_b, const float* __restrict__ mask_b,
    float* __restrict__ ws_off)
{
    // [row r][p01 0..65][granule j 0..31] of 16B; logical kul at j = kul^(p01&7)
    __shared__ uint4 stage[3 * 66 * 32];      // 101,376 B; aliased as red[]
    const int bid = blockIdx.x;
    const int row = (bid & 7) * 32 + (bid >> 3);
    const int b = row >> 6, ho = row & 63;
    const int tid = threadIdx.x;
    const int l = tid & 63;
    const int w = tid >> 6;
    const int lan = l & 31, h = l >> 5;
    const int ntile = w >> 2, kq = w & 3;

    // ---- stage 3 input rows ----
    const char* xtb = (const char*)xt + (size_t)b * 64 * 32768;
    for (int r = 0; r < 3; ++r) {
        int y = ho - 1 + r;
        uint4* rowbase = &stage[r * 66 * 32];
        if (y >= 0 && y < 64) {
            const char* src = xtb + (size_t)y * 32768;
            // interior granules 32..2079 (p01 1..64): 32 chunks of 64;
            // wave w stages chunks w*4 .. w*4+3 (dest wave-uniform+lane*16)
#pragma unroll
            for (int i = 0; i < 4; ++i) {
                int g0 = 32 + (w * 4 + i) * 64;
                int g = g0 + l;
                int p01 = g >> 5, j = g & 31;
                int kul = j ^ (p01 & 7);
                gl_lds16(src + ((size_t)(p01 - 1) * 32 + kul) * 16,
                         rowbase + g0);
            }
            // zero pads p01=0 (granules 0..31) and p01=65 (2080..2111)
            if (tid < 64) {
                int g = (tid < 32) ? tid : (2080 + (tid - 32));
                rowbase[g] = make_uint4(0, 0, 0, 0);
            }
        } else {
            for (int g = tid; g < 2112; g += 512)
                rowbase[g] = make_uint4(0, 0, 0, 0);
        }
    }
    __syncthreads();                  // DMA drained; stage complete

    floatx16 acc;
#pragma unroll
    for (int r = 0; r < 16; ++r) acc[r] = 0.f;

    const uint4* a4 = (const uint4*)ws_a2;
    const int n = ntile * 32 + lan;   // output pixel for this lane
#pragma unroll
    for (int ky = 0; ky < 3; ++ky) {
#pragma unroll
        for (int kx = 0; kx < 3; ++kx) {
            int kk = ky * 3 + kx;
            int p01 = n + kx;
#pragma unroll
            for (int s4 = 0; s4 < 4; ++s4) {
                int s = kq * 4 + s4;          // K-step 0..15 within chunk
                int kul = s * 2 + h;          // local ku 0..31
                uint4 ua = a4[(size_t)(kk * 32 + kul) * 32 + lan];
                uint4 ub = stage[(ky * 66 + p01) * 32 + (kul ^ (p01 & 7))];
                half8 a, bb;
                __builtin_memcpy(&a, &ua, 16);
                __builtin_memcpy(&bb, &ub, 16);
                acc = __builtin_amdgcn_mfma_f32_32x32x16_f16(a, bb, acc, 0, 0, 0);
            }
        }
    }
    __syncthreads();                  // all waves done reading stage

    // cross-wave partial-C reduction (4 K-quarters per n-tile) - verbatim r9
    float* red = (float*)stage;       // 8 waves x 64 lanes x 16 = 32 KiB
#pragma unroll
    for (int r = 0; r < 16; ++r) red[(w * 64 + l) * 16 + r] = acc[r];
    __syncthreads();
    for (int idx = tid; idx < 27 * 64; idx += 512) {
        int oc = idx >> 6, wo = idx & 63;
        int nt2 = wo >> 5, nn = wo & 31;
        int h2 = (oc >> 2) & 1;
        int r = (oc & 3) | ((oc >> 3) << 2);
        int lane2 = nn + 32 * h2;
        float s = 0.f;
#pragma unroll
        for (int kq2 = 0; kq2 < 4; ++kq2)
            s += red[((nt2 * 4 + kq2) * 64 + lane2) * 16 + r];
        float v;
        if (oc < 18) {
            v = s + off_b[oc];
        } else {
            float t = s + mask_b[oc - 18];
            v = 1.f / (1.f + expf(-t));
        }
        ws_off[(size_t)row * 1728 + idx] = v;
    }
}

// ---------------------------------------------------------------------------
// K3: fused deformable sampling + GEMM, software-pipelined, 2 blocks/CU.
// 256 blocks, 512 threads / 8 waves, 64 px/block.  LDS 80384 B.
// ---------------------------------------------------------------------------
__global__ __launch_bounds__(512, 4) void deform_gemm_kernel(
    const unsigned short* __restrict__ xt, const float* __restrict__ ws_off,
    const unsigned short* __restrict__ ws_b, const float* __restrict__ bias,
    float* __restrict__ out)
{
    __shared__ float4 paramw[576];      // per (tap,px): 4 corner weights
    __shared__ ushort4 paramo[576];     // per (tap,px): 4 clamped pixel indices
    __shared__ float biasl[256];
    __shared__ uint4 tile[2][2048];     // [buf][ku(32)*64 + n], XOR-swizzled

    const int bid = blockIdx.x;
    const int row = (bid & 7) * 32 + (bid >> 3);
    const int b = row >> 6, ho = row & 63;
    const int tid = threadIdx.x;
    const int l = tid & 63;
    const int wid = tid >> 6;          // 0..7
    const int lan = l & 31;            // channel-group (producer) / MFMA lane
    const int h = l >> 5;              // pixel-parity (producer) / MFMA K-half

    if (tid < 256) biasl[tid] = bias[tid];

    // ---- per-(tap,pixel) sampling params: weights + clamped corner indices
    {
        const float* ob = ws_off + (size_t)row * 1728;
        for (int it = tid; it < 576; it += 512) {
            int kk = it >> 6, p = it & 63;
            float dy = ob[(2 * kk) * 64 + p];
            float dx = ob[(2 * kk + 1) * 64 + p];
            float mk = ob[(18 + kk) * 64 + p];
            int ky = kk / 3, kx = kk - ky * 3;
            float py = (float)(ho - 1 + ky) + dy;
            float px = (float)(p - 1 + kx) + dx;
            float y0f = floorf(py), x0f = floorf(px);
            float wy1 = py - y0f, wx1 = px - x0f;
            float wy0 = 1.f - wy1, wx0 = 1.f - wx1;
            int y0 = (int)y0f, xi0 = (int)x0f;
            int y1 = y0 + 1, xi1 = xi0 + 1;
            float vy0 = (y0 >= 0 && y0 < 64) ? 1.f : 0.f;
            float vy1 = (y1 >= 0 && y1 < 64) ? 1.f : 0.f;
            float vx0 = (xi0 >= 0 && xi0 < 64) ? 1.f : 0.f;
            float vx1 = (xi1 >= 0 && xi1 < 64) ? 1.f : 0.f;
            float wr0 = wy0 * vy0 * mk, wr1 = wy1 * vy1 * mk;
            float wa = wx0 * vx0, wb2 = wx1 * vx1;
            int yc0 = min(max(y0, 0), 63), yc1 = min(max(y1, 0), 63);
            int xc0 = min(max(xi0, 0), 63), xc1 = min(max(xi1, 0), 63);
            paramw[it] = make_float4(wr0 * wa, wr0 * wb2, wr1 * wa, wr1 * wb2);
            paramo[it] = make_ushort4((unsigned short)(yc0 * 64 + xc0),
                                      (unsigned short)(yc0 * 64 + xc1),
                                      (unsigned short)(yc1 * 64 + xc0),
                                      (unsigned short)(yc1 * 64 + xc1));
        }
    }
    __syncthreads();

    const char* xb16 = (const char*)xt + ((size_t)b << 21);   // b * 2 MiB
    const uint4* wb4 = (const uint4*)ws_b;

    floatx16 acc0, acc1;
#pragma unroll
    for (int r = 0; r < 16; ++r) { acc0[r] = 0.f; acc1[r] = 0.f; }

    // pipeline register state: 2-pixel gather half-batches
    uint4 gA[2][4], gB[2][4];
    float4 wvA[2], wvB[2];
    uint4 ua[8];

    auto issue_half = [&](int kk, int i0, uint4 (&g)[2][4], float4 (&wv)[2]) {
#pragma unroll
        for (int i = 0; i < 2; ++i) {
            int p = wid * 8 + 2 * (i0 + i) + h;
            int e = kk * 64 + p;
            wv[i] = paramw[e];
            ushort4 uo = paramo[e];
            __builtin_memcpy(&g[i][0], xb16 + ((int)uo.x << 9) + (lan << 4), 16);
            __builtin_memcpy(&g[i][1], xb16 + ((int)uo.y << 9) + (lan << 4), 16);
            __builtin_memcpy(&g[i][2], xb16 + ((int)uo.z << 9) + (lan << 4), 16);
            __builtin_memcpy(&g[i][3], xb16 + ((int)uo.w << 9) + (lan << 4), 16);
        }
    };

    auto pack_half = [&](int buf, int i0, uint4 (&g)[2][4], float4 (&wv)[2]) {
        char* tb = (char*)&tile[buf][0];
#pragma unroll
        for (int i = 0; i < 2; ++i) {
            int p = wid * 8 + 2 * (i0 + i) + h;
            half8 h00, h01, h10, h11;
            __builtin_memcpy(&h00, &g[i][0], 16);
            __builtin_memcpy(&h01, &g[i][1], 16);
            __builtin_memcpy(&h10, &g[i][2], 16);
            __builtin_memcpy(&h11, &g[i][3], 16);
            unsigned pk[4];
#pragma unroll
            for (int j = 0; j < 4; ++j) {
                float v0 = wv[i].x * (float)h00[2 * j]     + wv[i].y * (float)h01[2 * j]
                         + wv[i].z * (float)h10[2 * j]     + wv[i].w * (float)h11[2 * j];
                float v1 = wv[i].x * (float)h00[2 * j + 1] + wv[i].y * (float)h01[2 * j + 1]
                         + wv[i].z * (float)h10[2 * j + 1] + wv[i].w * (float)h11[2 * j + 1];
                pk[j] = pack_bf16(v0, v1);
            }
            uint4 wv4 = make_uint4(pk[0], pk[1], pk[2], pk[3]);
            __builtin_memcpy(tb + lan * 1024 + ((p << 4) ^ (lan << 4)), &wv4, 16);
        }
    };

    // prologue: build tile[0] for tap 0
    issue_half(0, 0, gA, wvA);
    pack_half(0, 0, gA, wvA);
    issue_half(0, 2, gB, wvB);
    pack_half(0, 2, gB, wvB);
    __syncthreads();

    for (int kk = 0; kk < 9; ++kk) {
        const int buf = kk & 1, nbuf = (kk + 1) & 1;

        // ua batch 1 (ks 0..7), then next tap's gather half A, then ua batch 2
        // is loaded between the MFMA halves.  vmcnt order: ua1, gA, ua2, gB.
#pragma unroll
        for (int ks = 0; ks < 8; ++ks) {
            int kul = ks * 2 + h;
            ua[ks] = wb4[((size_t)wid * 288 + kk * 32 + kul) * 32 + lan];
        }
        if (kk < 8) issue_half(kk + 1, 0, gA, wvA);

        {   // MFMA ks 0..7 (waits ua1; gA stays in flight)
            const char* tb = (const char*)&tile[buf][0];
#pragma unroll
            for (int ks = 0; ks < 8; ++ks) {
                int kul = ks * 2 + h;
                uint4 ub0, ub1;
                __builtin_memcpy(&ub0, tb + kul * 1024 + ((lan << 4) ^ (kul << 4)), 16);
                __builtin_memcpy(&ub1, tb + kul * 1024 + (((32 + lan) << 4) ^ (kul << 4)), 16);
                short8 a, b0, b1;
                __builtin_memcpy(&a, &ua[ks], 16);
                __builtin_memcpy(&b0, &ub0, 16);
                __builtin_memcpy(&b1, &ub1, 16);
                acc0 = __builtin_amdgcn_mfma_f32_32x32x16_bf16(a, b0, acc0, 0, 0, 0);
                acc1 = __builtin_amdgcn_mfma_f32_32x32x16_bf16(a, b1, acc1, 0, 0, 0);
            }
        }

        // ua batch 2 (ks 8..15)
        uint4 ua2[8];
#pragma unroll
        for (int ks = 0; ks < 8; ++ks) {
            int kul = (ks + 8) * 2 + h;
            ua2[ks] = wb4[((size_t)wid * 288 + kk * 32 + kul) * 32 + lan];
        }

        if (kk < 8) {
            pack_half(nbuf, 0, gA, wvA);     // waits gA; ua2 stays in flight
            issue_half(kk + 1, 2, gB, wvB);
        }

        {   // MFMA ks 8..15 (waits ua2; gB stays in flight)
            const char* tb = (const char*)&tile[buf][0];
#pragma unroll
            for (int ks = 0; ks < 8; ++ks) {
                int kul = (ks + 8) * 2 + h;
                uint4 ub0, ub1;
                __builtin_memcpy(&ub0, tb + kul * 1024 + ((lan << 4) ^ (kul << 4)), 16);
                __builtin_memcpy(&ub1, tb + kul * 1024 + (((32 + lan) << 4) ^ (kul << 4)), 16);
                short8 a, b0, b1;
                __builtin_memcpy(&a, &ua2[ks], 16);
                __builtin_memcpy(&b0, &ub0, 16);
                __builtin_memcpy(&b1, &ub1, 16);
                acc0 = __builtin_amdgcn_mfma_f32_32x32x16_bf16(a, b0, acc0, 0, 0, 0);
                acc1 = __builtin_amdgcn_mfma_f32_32x32x16_bf16(a, b1, acc1, 0, 0, 0);
            }
        }

        if (kk < 8) pack_half(nbuf, 2, gB, wvB);
        __syncthreads();
    }

    // epilogue: wave wid owns m-tile wid, 2 n-tiles (verbatim)
#pragma unroll
    for (int nt = 0; nt < 2; ++nt) {
#pragma unroll
        for (int r = 0; r < 16; ++r) {
            int o = wid * 32 + (r & 3) + 8 * (r >> 2) + 4 * h;
            int woo = nt * 32 + lan;
            float v = (nt == 0) ? acc0[r] : acc1[r];
            out[(((size_t)b * 256 + o) * 64 + ho) * 64 + woo] = v + biasl[o];
        }
    }
}

extern "C" void kernel_launch(void* const* d_in, const int* in_sizes, int n_in,
                              void* d_out, int out_size, void* d_ws, size_t ws_size,
                              hipStream_t stream) {
    const float* x      = (const float*)d_in[0];
    const float* weight = (const float*)d_in[1];
    const float* bias   = (const float*)d_in[2];
    const float* off_w  = (const float*)d_in[3];
    const float* off_b  = (const float*)d_in[4];
    const float* mask_w = (const float*)d_in[5];
    const float* mask_b = (const float*)d_in[6];
    float* out = (float*)d_out;

    float* ws_off = (float*)d_ws;                                      // 1,769,472 B
    unsigned short* ws_b  = (unsigned short*)((char*)d_ws + 1769472);  // 1,179,648 B
    unsigned short* ws_a2 = (unsigned short*)((char*)d_ws + 2949120);  //   147,456 B
    unsigned short* xt    = (unsigned short*)((char*)d_ws + 3096576);  // 8,388,608 B

    hipLaunchKernelGGL(weight_pack_kernel, dim3(100), dim3(256), 0, stream,
                       weight, off_w, mask_w, ws_b, ws_a2);
    hipLaunchKernelGGL(xpose_hwc_kernel, dim3(256), dim3(256), 0, stream,
                       x, xt);
    hipLaunchKernelGGL(offmask_mfma_kernel, dim3(256), dim3(512), 0, stream,
                       xt, ws_a2, off_b, mask_b, ws_off);
    hipLaunchKernelGGL(deform_gemm_kernel, dim3(256), dim3(512), 0, stream,
                       xt, ws_off, ws_b, bias, out);
}

// Round 6
// 129.649 us; speedup vs baseline: 2.1031x; 2.1031x over previous
//
#include <hip/hip_runtime.h>
#include <hip/hip_bf16.h>
#include <string.h>

// DeformableConv2d: B=4, C=256, O=256, H=W=64, K=3, pad=1, stride=1
// Round 16: K3 = r15's LDS diet WITHOUT the register cap (one change vs r15).
//   r15 post-mortem: __launch_bounds__(512,4) made the allocator collapse to
//   64 VGPR and spill the whole pipeline to scratch (FETCH 10->241MB, WRITE
//   16->229MB, dur 45->186us). The diet itself was fine (LDS 80384, absmax
//   bit-identical). Occupancy follows ACTUAL usage: LDS<=80KiB + VGPR<=128
//   -> 2 blocks/CU with plain __launch_bounds__(512) (r13/r14 naturally
//   compiled to exactly 128). So: keep params split + LDS 80384, drop the
//   ",4", and reuse ONE ua[8] for both K-batches (smaller live range than
//   r14's ua[16]). vmcnt order per tap: U1, gatherA, U2, gatherB ->
//   MFMA1(waits U1, gA in flight), packA(waits gA, U2 in flight),
//   MFMA2(waits U2, gB in flight), packB. Arithmetic identical -> absmax
//   0.0078125.
// K0, K1, K2 byte-identical to round 14/15.
// Workspace: ws_off 1769472 | ws_b 1179648 | ws_a2 147456 | xt 8388608
//          = 11,485,184 B.

typedef __attribute__((ext_vector_type(8))) short short8;
typedef __attribute__((ext_vector_type(8))) _Float16 half8;
typedef __attribute__((ext_vector_type(16))) float floatx16;

__device__ __forceinline__ unsigned bfbits(float f) {
    unsigned u;
    __builtin_memcpy(&u, &f, 4);
    return (u + 0x7fffu + ((u >> 16) & 1u)) >> 16;   // RNE f32->bf16
}
__device__ __forceinline__ unsigned pack_bf16(float lo, float hi) {
    return bfbits(lo) | (bfbits(hi) << 16);
}
__device__ __forceinline__ unsigned pack_f16(float lo, float hi) {
    _Float16 a = (_Float16)lo, b = (_Float16)hi;
    unsigned short ua, ub;
    __builtin_memcpy(&ua, &a, 2);
    __builtin_memcpy(&ub, &b, 2);
    return (unsigned)ua | ((unsigned)ub << 16);
}

// async global->LDS DMA, 16 B per lane; lane l's data lands at lds + l*16.
// Global source address is PER-LANE (enables write-side swizzle).
__device__ __forceinline__ void gl_lds16(const void* g, void* l) {
    __builtin_amdgcn_global_load_lds(
        (const __attribute__((address_space(1))) unsigned int*)g,
        (__attribute__((address_space(3))) unsigned int*)l,
        16, 0, 0);
}

// ---------------------------------------------------------------------------
// K0: x (B,C,H,W) f32 -> xt (B,H,W,C) f16.  One block per (b, y) row.
// (verbatim rounds 12-15)
// ---------------------------------------------------------------------------
__global__ __launch_bounds__(256) void xpose_hwc_kernel(
    const float* __restrict__ x, unsigned short* __restrict__ xt)
{
    __shared__ float stage[256 * 65];
    const int bid = blockIdx.x;          // (b*64 + y)
    const int b = bid >> 6, y = bid & 63;
    const int tid = threadIdx.x;
    const float* src = x + (size_t)b * 256 * 4096 + y * 64;

#pragma unroll
    for (int i = 0; i < 16; ++i) {
        int idx = i * 256 + tid;         // 0..4095 = (c, xq)
        int c = idx >> 4, xq = idx & 15;
        float4 v = *(const float4*)&src[(size_t)c * 4096 + xq * 4];
        stage[c * 65 + xq * 4 + 0] = v.x;
        stage[c * 65 + xq * 4 + 1] = v.y;
        stage[c * 65 + xq * 4 + 2] = v.z;
        stage[c * 65 + xq * 4 + 3] = v.w;
    }
    __syncthreads();

    unsigned short* dst = xt + (size_t)bid * 16384;   // 64 px * 256 ch
#pragma unroll
    for (int i = 0; i < 32; ++i) {
        int c2 = (tid & 127) * 2;
        int xx = i * 2 + (tid >> 7);
        float f0 = stage[c2 * 65 + xx];
        float f1 = stage[(c2 + 1) * 65 + xx];
        *(unsigned*)&dst[xx * 256 + c2] = pack_f16(f0, f1);
    }
}

// ---------------------------------------------------------------------------
// K1: weight pack (verbatim rounds 4-15).
// ---------------------------------------------------------------------------
__global__ __launch_bounds__(256) void weight_pack_kernel(
    const float* __restrict__ w, const float* __restrict__ off_w,
    const float* __restrict__ mask_w,
    unsigned short* __restrict__ ws_b, unsigned short* __restrict__ ws_a2)
{
    __shared__ float slab[32 * 289];
    const int bid = blockIdx.x;
    const int tid = threadIdx.x;

    if (bid < 64) {
        const int nt = bid >> 3, cb = bid & 7;
        const float* wbase = w + (size_t)nt * 32 * 2304 + cb * 288;
#pragma unroll
        for (int i = 0; i < 9; ++i) {
            int idx = i * 256 + tid;               // 0..2303
            int o = idx / 72, f4 = idx % 72;
            float4 v = *(const float4*)&wbase[(size_t)o * 2304 + f4 * 4];
            slab[o * 289 + f4 * 4 + 0] = v.x;
            slab[o * 289 + f4 * 4 + 1] = v.y;
            slab[o * 289 + f4 * 4 + 2] = v.z;
            slab[o * 289 + f4 * 4 + 3] = v.w;
        }
        __syncthreads();
#pragma unroll
        for (int pass = 0; pass < 5; ++pass) {
            int rid = pass * 8 + (tid >> 5);
            if (rid < 36) {
                int kk = rid >> 2, q = rid & 3;
                int no = tid & 31;
                unsigned pk[4];
#pragma unroll
                for (int i = 0; i < 4; ++i) {
                    float f0 = slab[no * 289 + (q * 8 + 2 * i) * 9 + kk];
                    float f1 = slab[no * 289 + (q * 8 + 2 * i + 1) * 9 + kk];
                    pk[i] = pack_bf16(f0, f1);
                }
                size_t u = ((size_t)nt * 288 + kk * 32 + cb * 4 + q) * 32 + no;
                *(uint4*)&ws_b[u * 8] = make_uint4(pk[0], pk[1], pk[2], pk[3]);
            }
        }
    } else {
        int e = (bid - 64) * 256 + tid;       // 0..9215
        int lan = e & 31;                     // oc row
        int ku = e >> 5;                      // 0..287
        int kk = ku >> 5;
        int c0 = (ku & 31) * 8;
        int o = lan;
        float f[8];
#pragma unroll
        for (int j = 0; j < 8; ++j) {
            int c = c0 + j;
            float v = 0.f;
            if (o < 18)      v = off_w[((size_t)o * 256 + c) * 9 + kk];
            else if (o < 27) v = mask_w[((size_t)(o - 18) * 256 + c) * 9 + kk];
            f[j] = v;
        }
        unsigned pk[4];
#pragma unroll
        for (int i = 0; i < 4; ++i) pk[i] = pack_f16(f[2 * i], f[2 * i + 1]);
        *(uint4*)&ws_a2[(size_t)e * 8] = make_uint4(pk[0], pk[1], pk[2], pk[3]);
    }
}

// ---------------------------------------------------------------------------
// K2: offset/mask conv, xt-direct edition (verbatim rounds 14-15).
// ---------------------------------------------------------------------------
__global__ __launch_bounds__(512) void offmask_mfma_kernel(
    const unsigned short* __restrict__ xt, const unsigned short* __restrict__ ws_a2,
    const float* __restrict__ off_b, const float* __restrict__ mask_b,
    float* __restrict__ ws_off)
{
    // [row r][p01 0..65][granule j 0..31] of 16B; logical kul at j = kul^(p01&7)
    __shared__ uint4 stage[3 * 66 * 32];      // 101,376 B; aliased as red[]
    const int bid = blockIdx.x;
    const int row = (bid & 7) * 32 + (bid >> 3);
    const int b = row >> 6, ho = row & 63;
    const int tid = threadIdx.x;
    const int l = tid & 63;
    const int w = tid >> 6;
    const int lan = l & 31, h = l >> 5;
    const int ntile = w >> 2, kq = w & 3;

    // ---- stage 3 input rows ----
    const char* xtb = (const char*)xt + (size_t)b * 64 * 32768;
    for (int r = 0; r < 3; ++r) {
        int y = ho - 1 + r;
        uint4* rowbase = &stage[r * 66 * 32];
        if (y >= 0 && y < 64) {
            const char* src = xtb + (size_t)y * 32768;
            // interior granules 32..2079 (p01 1..64): 32 chunks of 64;
            // wave w stages chunks w*4 .. w*4+3 (dest wave-uniform+lane*16)
#pragma unroll
            for (int i = 0; i < 4; ++i) {
                int g0 = 32 + (w * 4 + i) * 64;
                int g = g0 + l;
                int p01 = g >> 5, j = g & 31;
                int kul = j ^ (p01 & 7);
                gl_lds16(src + ((size_t)(p01 - 1) * 32 + kul) * 16,
                         rowbase + g0);
            }
            // zero pads p01=0 (granules 0..31) and p01=65 (2080..2111)
            if (tid < 64) {
                int g = (tid < 32) ? tid : (2080 + (tid - 32));
                rowbase[g] = make_uint4(0, 0, 0, 0);
            }
        } else {
            for (int g = tid; g < 2112; g += 512)
                rowbase[g] = make_uint4(0, 0, 0, 0);
        }
    }
    __syncthreads();                  // DMA drained; stage complete

    floatx16 acc;
#pragma unroll
    for (int r = 0; r < 16; ++r) acc[r] = 0.f;

    const uint4* a4 = (const uint4*)ws_a2;
    const int n = ntile * 32 + lan;   // output pixel for this lane
#pragma unroll
    for (int ky = 0; ky < 3; ++ky) {
#pragma unroll
        for (int kx = 0; kx < 3; ++kx) {
            int kk = ky * 3 + kx;
            int p01 = n + kx;
#pragma unroll
            for (int s4 = 0; s4 < 4; ++s4) {
                int s = kq * 4 + s4;          // K-step 0..15 within chunk
                int kul = s * 2 + h;          // local ku 0..31
                uint4 ua = a4[(size_t)(kk * 32 + kul) * 32 + lan];
                uint4 ub = stage[(ky * 66 + p01) * 32 + (kul ^ (p01 & 7))];
                half8 a, bb;
                __builtin_memcpy(&a, &ua, 16);
                __builtin_memcpy(&bb, &ub, 16);
                acc = __builtin_amdgcn_mfma_f32_32x32x16_f16(a, bb, acc, 0, 0, 0);
            }
        }
    }
    __syncthreads();                  // all waves done reading stage

    // cross-wave partial-C reduction (4 K-quarters per n-tile) - verbatim r9
    float* red = (float*)stage;       // 8 waves x 64 lanes x 16 = 32 KiB
#pragma unroll
    for (int r = 0; r < 16; ++r) red[(w * 64 + l) * 16 + r] = acc[r];
    __syncthreads();
    for (int idx = tid; idx < 27 * 64; idx += 512) {
        int oc = idx >> 6, wo = idx & 63;
        int nt2 = wo >> 5, nn = wo & 31;
        int h2 = (oc >> 2) & 1;
        int r = (oc & 3) | ((oc >> 3) << 2);
        int lane2 = nn + 32 * h2;
        float s = 0.f;
#pragma unroll
        for (int kq2 = 0; kq2 < 4; ++kq2)
            s += red[((nt2 * 4 + kq2) * 64 + lane2) * 16 + r];
        float v;
        if (oc < 18) {
            v = s + off_b[oc];
        } else {
            float t = s + mask_b[oc - 18];
            v = 1.f / (1.f + expf(-t));
        }
        ws_off[(size_t)row * 1728 + idx] = v;
    }
}

// ---------------------------------------------------------------------------
// K3: fused deformable sampling + GEMM, software-pipelined, LDS 80384 B.
// 256 blocks, 512 threads / 8 waves, 64 px/block.  No register cap: the
// allocator lands at its natural ~128 VGPR (r13/r14 behavior); with LDS
// under 80 KiB that yields 2 blocks/CU at dispatch.
// ---------------------------------------------------------------------------
__global__ __launch_bounds__(512) void deform_gemm_kernel(
    const unsigned short* __restrict__ xt, const float* __restrict__ ws_off,
    const unsigned short* __restrict__ ws_b, const float* __restrict__ bias,
    float* __restrict__ out)
{
    __shared__ float4 paramw[576];      // per (tap,px): 4 corner weights
    __shared__ ushort4 paramo[576];     // per (tap,px): 4 clamped pixel indices
    __shared__ float biasl[256];
    __shared__ uint4 tile[2][2048];     // [buf][ku(32)*64 + n], XOR-swizzled

    const int bid = blockIdx.x;
    const int row = (bid & 7) * 32 + (bid >> 3);
    const int b = row >> 6, ho = row & 63;
    const int tid = threadIdx.x;
    const int l = tid & 63;
    const int wid = tid >> 6;          // 0..7
    const int lan = l & 31;            // channel-group (producer) / MFMA lane
    const int h = l >> 5;              // pixel-parity (producer) / MFMA K-half

    if (tid < 256) biasl[tid] = bias[tid];

    // ---- per-(tap,pixel) sampling params: weights + clamped corner indices
    {
        const float* ob = ws_off + (size_t)row * 1728;
        for (int it = tid; it < 576; it += 512) {
            int kk = it >> 6, p = it & 63;
            float dy = ob[(2 * kk) * 64 + p];
            float dx = ob[(2 * kk + 1) * 64 + p];
            float mk = ob[(18 + kk) * 64 + p];
            int ky = kk / 3, kx = kk - ky * 3;
            float py = (float)(ho - 1 + ky) + dy;
            float px = (float)(p - 1 + kx) + dx;
            float y0f = floorf(py), x0f = floorf(px);
            float wy1 = py - y0f, wx1 = px - x0f;
            float wy0 = 1.f - wy1, wx0 = 1.f - wx1;
            int y0 = (int)y0f, xi0 = (int)x0f;
            int y1 = y0 + 1, xi1 = xi0 + 1;
            float vy0 = (y0 >= 0 && y0 < 64) ? 1.f : 0.f;
            float vy1 = (y1 >= 0 && y1 < 64) ? 1.f : 0.f;
            float vx0 = (xi0 >= 0 && xi0 < 64) ? 1.f : 0.f;
            float vx1 = (xi1 >= 0 && xi1 < 64) ? 1.f : 0.f;
            float wr0 = wy0 * vy0 * mk, wr1 = wy1 * vy1 * mk;
            float wa = wx0 * vx0, wb2 = wx1 * vx1;
            int yc0 = min(max(y0, 0), 63), yc1 = min(max(y1, 0), 63);
            int xc0 = min(max(xi0, 0), 63), xc1 = min(max(xi1, 0), 63);
            paramw[it] = make_float4(wr0 * wa, wr0 * wb2, wr1 * wa, wr1 * wb2);
            paramo[it] = make_ushort4((unsigned short)(yc0 * 64 + xc0),
                                      (unsigned short)(yc0 * 64 + xc1),
                                      (unsigned short)(yc1 * 64 + xc0),
                                      (unsigned short)(yc1 * 64 + xc1));
        }
    }
    __syncthreads();

    const char* xb16 = (const char*)xt + ((size_t)b << 21);   // b * 2 MiB
    const uint4* wb4 = (const uint4*)ws_b;

    floatx16 acc0, acc1;
#pragma unroll
    for (int r = 0; r < 16; ++r) { acc0[r] = 0.f; acc1[r] = 0.f; }

    // pipeline register state: 2-pixel gather half-batches
    uint4 gA[2][4], gB[2][4];
    float4 wvA[2], wvB[2];
    uint4 ua[8];                        // reused for both K-batches

    auto issue_half = [&](int kk, int i0, uint4 (&g)[2][4], float4 (&wv)[2]) {
#pragma unroll
        for (int i = 0; i < 2; ++i) {
            int p = wid * 8 + 2 * (i0 + i) + h;
            int e = kk * 64 + p;
            wv[i] = paramw[e];
            ushort4 uo = paramo[e];
            __builtin_memcpy(&g[i][0], xb16 + ((int)uo.x << 9) + (lan << 4), 16);
            __builtin_memcpy(&g[i][1], xb16 + ((int)uo.y << 9) + (lan << 4), 16);
            __builtin_memcpy(&g[i][2], xb16 + ((int)uo.z << 9) + (lan << 4), 16);
            __builtin_memcpy(&g[i][3], xb16 + ((int)uo.w << 9) + (lan << 4), 16);
        }
    };

    auto pack_half = [&](int buf, int i0, uint4 (&g)[2][4], float4 (&wv)[2]) {
        char* tb = (char*)&tile[buf][0];
#pragma unroll
        for (int i = 0; i < 2; ++i) {
            int p = wid * 8 + 2 * (i0 + i) + h;
            half8 h00, h01, h10, h11;
            __builtin_memcpy(&h00, &g[i][0], 16);
            __builtin_memcpy(&h01, &g[i][1], 16);
            __builtin_memcpy(&h10, &g[i][2], 16);
            __builtin_memcpy(&h11, &g[i][3], 16);
            unsigned pk[4];
#pragma unroll
            for (int j = 0; j < 4; ++j) {
                float v0 = wv[i].x * (float)h00[2 * j]     + wv[i].y * (float)h01[2 * j]
                         + wv[i].z * (float)h10[2 * j]     + wv[i].w * (float)h11[2 * j];
                float v1 = wv[i].x * (float)h00[2 * j + 1] + wv[i].y * (float)h01[2 * j + 1]
                         + wv[i].z * (float)h10[2 * j + 1] + wv[i].w * (float)h11[2 * j + 1];
                pk[j] = pack_bf16(v0, v1);
            }
            uint4 wv4 = make_uint4(pk[0], pk[1], pk[2], pk[3]);
            __builtin_memcpy(tb + lan * 1024 + ((p << 4) ^ (lan << 4)), &wv4, 16);
        }
    };

    // prologue: build tile[0] for tap 0
    issue_half(0, 0, gA, wvA);
    pack_half(0, 0, gA, wvA);
    issue_half(0, 2, gB, wvB);
    pack_half(0, 2, gB, wvB);
    __syncthreads();

    for (int kk = 0; kk < 9; ++kk) {
        const int buf = kk & 1, nbuf = (kk + 1) & 1;

        // ua batch 1 (ks 0..7); then next tap's gather half A.
        // vmcnt order per tap: U1, gA, U2, gB.
#pragma unroll
        for (int ks = 0; ks < 8; ++ks) {
            int kul = ks * 2 + h;
            ua[ks] = wb4[((size_t)wid * 288 + kk * 32 + kul) * 32 + lan];
        }
        if (kk < 8) issue_half(kk + 1, 0, gA, wvA);

        {   // MFMA ks 0..7 (waits U1; gA stays in flight)
            const char* tb = (const char*)&tile[buf][0];
#pragma unroll
            for (int ks = 0; ks < 8; ++ks) {
                int kul = ks * 2 + h;
                uint4 ub0, ub1;
                __builtin_memcpy(&ub0, tb + kul * 1024 + ((lan << 4) ^ (kul << 4)), 16);
                __builtin_memcpy(&ub1, tb + kul * 1024 + (((32 + lan) << 4) ^ (kul << 4)), 16);
                short8 a, b0, b1;
                __builtin_memcpy(&a, &ua[ks], 16);
                __builtin_memcpy(&b0, &ub0, 16);
                __builtin_memcpy(&b1, &ub1, 16);
                acc0 = __builtin_amdgcn_mfma_f32_32x32x16_bf16(a, b0, acc0, 0, 0, 0);
                acc1 = __builtin_amdgcn_mfma_f32_32x32x16_bf16(a, b1, acc1, 0, 0, 0);
            }
        }

        // ua batch 2 (ks 8..15) into the same registers (batch 1 consumed)
#pragma unroll
        for (int ks = 0; ks < 8; ++ks) {
            int kul = (ks + 8) * 2 + h;
            ua[ks] = wb4[((size_t)wid * 288 + kk * 32 + kul) * 32 + lan];
        }

        if (kk < 8) {
            pack_half(nbuf, 0, gA, wvA);     // waits gA; U2 stays in flight
            issue_half(kk + 1, 2, gB, wvB);
        }

        {   // MFMA ks 8..15 (waits U2; gB stays in flight)
            const char* tb = (const char*)&tile[buf][0];
#pragma unroll
            for (int ks = 0; ks < 8; ++ks) {
                int kul = (ks + 8) * 2 + h;
                uint4 ub0, ub1;
                __builtin_memcpy(&ub0, tb + kul * 1024 + ((lan << 4) ^ (kul << 4)), 16);
                __builtin_memcpy(&ub1, tb + kul * 1024 + (((32 + lan) << 4) ^ (kul << 4)), 16);
                short8 a, b0, b1;
                __builtin_memcpy(&a, &ua[ks], 16);
                __builtin_memcpy(&b0, &ub0, 16);
                __builtin_memcpy(&b1, &ub1, 16);
                acc0 = __builtin_amdgcn_mfma_f32_32x32x16_bf16(a, b0, acc0, 0, 0, 0);
                acc1 = __builtin_amdgcn_mfma_f32_32x32x16_bf16(a, b1, acc1, 0, 0, 0);
            }
        }

        if (kk < 8) pack_half(nbuf, 2, gB, wvB);
        __syncthreads();
    }

    // epilogue: wave wid owns m-tile wid, 2 n-tiles (verbatim)
#pragma unroll
    for (int nt = 0; nt < 2; ++nt) {
#pragma unroll
        for (int r = 0; r < 16; ++r) {
            int o = wid * 32 + (r & 3) + 8 * (r >> 2) + 4 * h;
            int woo = nt * 32 + lan;
            float v = (nt == 0) ? acc0[r] : acc1[r];
            out[(((size_t)b * 256 + o) * 64 + ho) * 64 + woo] = v + biasl[o];
        }
    }
}

extern "C" void kernel_launch(void* const* d_in, const int* in_sizes, int n_in,
                              void* d_out, int out_size, void* d_ws, size_t ws_size,
                              hipStream_t stream) {
    const float* x      = (const float*)d_in[0];
    const float* weight = (const float*)d_in[1];
    const float* bias   = (const float*)d_in[2];
    const float* off_w  = (const float*)d_in[3];
    const float* off_b  = (const float*)d_in[4];
    const float* mask_w = (const float*)d_in[5];
    const float* mask_b = (const float*)d_in[6];
    float* out = (float*)d_out;

    float* ws_off = (float*)d_ws;                                      // 1,769,472 B
    unsigned short* ws_b  = (unsigned short*)((char*)d_ws + 1769472);  // 1,179,648 B
    unsigned short* ws_a2 = (unsigned short*)((char*)d_ws + 2949120);  //   147,456 B
    unsigned short* xt    = (unsigned short*)((char*)d_ws + 3096576);  // 8,388,608 B

    hipLaunchKernelGGL(weight_pack_kernel, dim3(100), dim3(256), 0, stream,
                       weight, off_w, mask_w, ws_b, ws_a2);
    hipLaunchKernelGGL(xpose_hwc_kernel, dim3(256), dim3(256), 0, stream,
                       x, xt);
    hipLaunchKernelGGL(offmask_mfma_kernel, dim3(256), dim3(512), 0, stream,
                       xt, ws_a2, off_b, mask_b, ws_off);
    hipLaunchKernelGGL(deform_gemm_kernel, dim3(256), dim3(512), 0, stream,
                       xt, ws_off, ws_b, bias, out);
}